// Round 12
// baseline (8154.536 us; speedup 1.0000x reference)
//
#include <hip/hip_runtime.h>

typedef unsigned short u16;
typedef unsigned long long u64;
typedef __attribute__((ext_vector_type(8))) short short8;
typedef __attribute__((ext_vector_type(4))) float f32x4;

#define DEVINL __device__ __forceinline__

constexpr int Nb = 64;     // batch
constexpr int Tt = 1024;   // time
constexpr int Dd = 1024;   // input dim
constexpr int Hh = 1024;   // hidden
constexpr int NWG = 256;   // workgroups (== CUs)
constexpr int TPB = 256;   // threads per wg (4 waves)
constexpr int TWG = 128;   // wgs per team
constexpr int MS  = 32;    // samples per team

DEVINL u16 f2b(float f) {
  union { float f; unsigned u; } v; v.f = f;
  unsigned r = (v.u + 0x7fffu + ((v.u >> 16) & 1u)) >> 16;
  return (u16)r;
}
DEVINL float b2f(u16 b) {
  union { unsigned u; float f; } v; v.u = ((unsigned)b) << 16;
  return v.f;
}
DEVINL float sigm(float x) { return 1.f / (1.f + __expf(-x)); }
DEVINL float tanhfast(float x) { float e = __expf(2.f * x); return 1.f - 2.f / (e + 1.f); }

// IC-coherent (SC1) h-fragment load (fallback path only).
DEVINL short8 ldh16(const u16* p) {
  u64 a = __hip_atomic_load((const u64*)p,       __ATOMIC_RELAXED, __HIP_MEMORY_SCOPE_AGENT);
  u64 b = __hip_atomic_load((const u64*)(p + 4), __ATOMIC_RELAXED, __HIP_MEMORY_SCOPE_AGENT);
  union { u64 q[2]; short8 v; } u;
  u.q[0] = a; u.q[1] = b;
  return u.v;
}

// Raw LDS barrier: lgkmcnt drain + s_barrier; does NOT drain vmcnt.
DEVINL void bar_w() {
  asm volatile("s_waitcnt lgkmcnt(0)" ::: "memory");
  __builtin_amdgcn_s_barrier();
}

__global__ void cvt_x_kernel(const float* __restrict__ x, u16* __restrict__ xb) {
  size_t i = ((size_t)blockIdx.x * TPB + threadIdx.x) * 8;
  float4 a = *reinterpret_cast<const float4*>(x + i);
  float4 b = *reinterpret_cast<const float4*>(x + i + 4);
  short8 r;
  r[0] = (short)f2b(a.x); r[1] = (short)f2b(a.y);
  r[2] = (short)f2b(a.z); r[3] = (short)f2b(a.w);
  r[4] = (short)f2b(b.x); r[5] = (short)f2b(b.y);
  r[6] = (short)f2b(b.z); r[7] = (short)f2b(b.w);
  *reinterpret_cast<short8*>(xb + i) = r;
}

// Wx [1024][4096] f32 -> Wxt [4096][1024] bf16 (transpose for GEMM B^T).
__global__ void cvt_wt_kernel(const float* __restrict__ wx, u16* __restrict__ wxt) {
  int gid = blockIdx.x * TPB + threadIdx.x;   // 524288 threads x 8 elems
  int k  = gid >> 9;
  int nb = (gid & 511) * 8;
  const float* p = wx + (size_t)k * 4096 + nb;
  #pragma unroll
  for (int i = 0; i < 8; ++i)
    wxt[(size_t)(nb + i) * 1024 + k] = f2b(p[i]);
}

// xW[m][n] = xb[m][:1024] @ Wxt[n][:1024]^T  (i.e. x @ Wx), m = n_sample*1024+t.
// 128x128 tile, BK=32, double-buffered padded LDS ([128][40]: 80B row stride,
// 16B-aligned b128 reads, 2-way-free bank pattern), 1 barrier/k-step.
// STAGING (r11 bugfix): 4096 elems/tile / 256 thr = 16 elems/thread -> TWO
// short8 passes: pass rr covers rows rr*64+(tid>>2), cols (tid&3)*8..+8.
template<bool F32OUT>
__global__ __launch_bounds__(TPB) void gemm_xw(
    const u16* __restrict__ A, const u16* __restrict__ B, void* __restrict__ C)
{
  __shared__ u16 Al[2][128][40];
  __shared__ u16 Bl[2][128][40];
  const int tid = threadIdx.x;
  const int w = tid >> 6, l = tid & 63;
  const int mt = blockIdx.x >> 5, nt = blockIdx.x & 31;
  const size_t m0 = (size_t)mt * 128, n0 = (size_t)nt * 128;
  const int wr = w >> 1, wc = w & 1;          // 2x2 wave grid, 64x64 each
  const int srow = tid >> 2;                  // 0..63
  const int scol = (tid & 3) * 8;             // 0,8,16,24
  const int arow = l & 15, kg = (l >> 4) * 8;

  f32x4 acc[4][4];
  #pragma unroll
  for (int i = 0; i < 4; ++i)
    #pragma unroll
    for (int j = 0; j < 4; ++j) acc[i][j] = (f32x4){0.f, 0.f, 0.f, 0.f};

  // prologue: stage k-step 0 (full coverage: 2 row-half passes)
  #pragma unroll
  for (int rr = 0; rr < 2; ++rr) {
    int row = rr * 64 + srow;
    short8 sa = *reinterpret_cast<const short8*>(A + (m0 + row) * 1024 + scol);
    short8 sb = *reinterpret_cast<const short8*>(B + (n0 + row) * 1024 + scol);
    *reinterpret_cast<short8*>(&Al[0][row][scol]) = sa;
    *reinterpret_cast<short8*>(&Bl[0][row][scol]) = sb;
  }
  bar_w();

  int cur = 0;
  for (int ks = 0; ks < 32; ++ks) {
    short8 na[2], nb2[2];
    if (ks < 31) {
      #pragma unroll
      for (int rr = 0; rr < 2; ++rr) {
        int row = rr * 64 + srow;
        na[rr]  = *reinterpret_cast<const short8*>(A + (m0 + row) * 1024 + (ks + 1) * 32 + scol);
        nb2[rr] = *reinterpret_cast<const short8*>(B + (n0 + row) * 1024 + (ks + 1) * 32 + scol);
      }
    }
    short8 av[4], bv[4];
    #pragma unroll
    for (int tr = 0; tr < 4; ++tr)
      av[tr] = *reinterpret_cast<const short8*>(&Al[cur][wr * 64 + tr * 16 + arow][kg]);
    #pragma unroll
    for (int tc = 0; tc < 4; ++tc)
      bv[tc] = *reinterpret_cast<const short8*>(&Bl[cur][wc * 64 + tc * 16 + arow][kg]);
    #pragma unroll
    for (int tr = 0; tr < 4; ++tr)
      #pragma unroll
      for (int tc = 0; tc < 4; ++tc)
        acc[tr][tc] = __builtin_amdgcn_mfma_f32_16x16x32_bf16(av[tr], bv[tc], acc[tr][tc], 0, 0, 0);
    if (ks < 31) {
      #pragma unroll
      for (int rr = 0; rr < 2; ++rr) {
        int row = rr * 64 + srow;
        *reinterpret_cast<short8*>(&Al[cur ^ 1][row][scol]) = na[rr];
        *reinterpret_cast<short8*>(&Bl[cur ^ 1][row][scol]) = nb2[rr];
      }
    }
    bar_w();
    cur ^= 1;
  }

  #pragma unroll
  for (int tr = 0; tr < 4; ++tr) {
    int mrow = wr * 64 + tr * 16 + 4 * (l >> 4);
    #pragma unroll
    for (int tc = 0; tc < 4; ++tc) {
      int ncol = wc * 64 + tc * 16 + (l & 15);
      #pragma unroll
      for (int q = 0; q < 4; ++q) {
        size_t off = (m0 + mrow + q) * 4096 + n0 + ncol;
        if constexpr (F32OUT) ((float*)C)[off] = acc[tr][tc][q];
        else                  ((u16*)C)[off]   = f2b(acc[tr][tc][q]);
      }
    }
  }
}

// MODE 0: r10 behavior (x in loop). MODE 1: xW precomputed f32. MODE 2: bf16.
// Protocol (unchanged from r10): SC1 publish + flags, HIST fresh-address
// cached h reads, Gate A (per-wave poll of its 32 producers), Gate B
// (pubcnt WAR), symmetric publish, single barrier per step.
template<int MODE, bool XBF16, bool HIST>
__global__ __launch_bounds__(TPB, 1) void lstm_team(
    const float* __restrict__ x, const u16* __restrict__ xb,
    const float* __restrict__ h0, const float* __restrict__ Wx,
    const float* __restrict__ Wh, const float* __restrict__ bias,
    float* __restrict__ out, u16* __restrict__ hmem,
    unsigned* __restrict__ flg, const void* __restrict__ xw)
{
  __shared__ u16 Bt[32][2048];       // staging (MODE>=1 uses first half)
  __shared__ float ex[4][32][36];
  __shared__ unsigned pubcnt;

  const int g   = blockIdx.x;
  const int tid = threadIdx.x;
  const int w   = tid >> 6;
  const int l   = tid & 63;

  const int team = ((g & 7) < 4) ? 0 : 1;
  const int r    = (g >> 3) * 4 + (g & 3);
  const int n0   = team * MS;
  const int jc0  = r * 8;

  unsigned* tFlg = flg + team * TWG;
  u16* hb0 = HIST ? hmem + (size_t)team * ((size_t)Tt * MS * Hh)
                  : hmem + (size_t)team * (2 * MS * Hh);

  if (tid == 0) pubcnt = 0u;

  // ---- one-time: weight column slice -> LDS bf16, swizzled ----
  constexpr int KW = (MODE == 0) ? 2048 : 1024;
  for (int idx = tid; idx < 32 * KW; idx += TPB) {
    int k = idx / 32;
    int c = idx & 31;
    int pc = (c >> 3) * 1024 + jc0 + (c & 7);
    float v;
    if constexpr (MODE == 0)
      v = (k < 1024) ? Wh[(size_t)k * 4096 + pc] : Wx[(size_t)(k - 1024) * 4096 + pc];
    else
      v = Wh[(size_t)k * 4096 + pc];
    Bt[c][k ^ ((c & 7) << 3)] = f2b(v);
  }

  // ---- one-time init, SAME ownership as main-loop h-stores ----
  if (tid < 64) {
    int n  = tid >> 1;
    int jc = (tid & 1) * 4;
    const float* hp = h0 + (size_t)(n0 + n) * Hh + jc0 + jc;
    u64 pk = (u64)f2b(hp[0]) | ((u64)f2b(hp[1]) << 16) |
             ((u64)f2b(hp[2]) << 32) | ((u64)f2b(hp[3]) << 48);
    __hip_atomic_store((u64*)(hb0 + n * Hh + jc0 + jc), pk,
                       __ATOMIC_RELAXED, __HIP_MEMORY_SCOPE_AGENT);
    asm volatile("s_waitcnt vmcnt(0)" ::: "memory");
    if (tid == 0)
      __hip_atomic_store(&tFlg[r], 1u, __ATOMIC_RELAXED, __HIP_MEMORY_SCOPE_AGENT);
  }
  __syncthreads();

  const int jj = tid & 7;
  const int nE = tid >> 3;
  const float bI = bias[0 * 1024 + jc0 + jj];
  const float bF = bias[1 * 1024 + jc0 + jj];
  const float bO = bias[2 * 1024 + jc0 + jj];
  const float bG = bias[3 * 1024 + jc0 + jj];
  float c_reg = 0.f;

  const int arow = l & 15;
  const int kg   = (l >> 4) * 8;
  const int kb   = w * 256;              // h K-slice base
  const int sw   = (l & 7) << 3;
  const u16* bp0 = &Bt[l & 15][0];
  const u16* bp1 = &Bt[16 | (l & 15)][0];

  // ---- hoist loop-invariant B-fragments ----
  short8 bh0[8], bh1[8], bx0[8], bx1[8];
  #pragma unroll
  for (int i = 0; i < 8; ++i) {
    int ka = (kb + kg + 32 * i) ^ sw;
    bh0[i] = *reinterpret_cast<const short8*>(bp0 + ka);
    bh1[i] = *reinterpret_cast<const short8*>(bp1 + ka);
    if constexpr (MODE == 0) {
      int kx = (1024 + kb + kg + 32 * i) ^ sw;
      bx0[i] = *reinterpret_cast<const short8*>(bp0 + kx);
      bx1[i] = *reinterpret_cast<const short8*>(bp1 + kx);
    }
  }

  for (int t = 0; t < Tt; ++t) {
    const u16* hb  = HIST ? hb0 + (size_t)t * (MS * Hh) : hb0 + (t & 1) * (MS * Hh);
    u16*       hbn = HIST ? hb0 + (size_t)(t + 1) * (MS * Hh) : hb0 + ((t + 1) & 1) * (MS * Hh);

    f32x4 a00 = {0.f,0.f,0.f,0.f}, a01 = {0.f,0.f,0.f,0.f};
    f32x4 a10 = {0.f,0.f,0.f,0.f}, a11 = {0.f,0.f,0.f,0.f};
    float xwv0 = 0.f, xwv1 = 0.f, xwv2 = 0.f, xwv3 = 0.f;

    if constexpr (MODE == 0) {
      short8 xv0[8], xv1[8];
      if constexpr (XBF16) {
        const u16* xr0 = xb + ((size_t)(n0 + arow)      * Tt + t) * Dd + kb + kg;
        const u16* xr1 = xb + ((size_t)(n0 + 16 + arow) * Tt + t) * Dd + kb + kg;
        #pragma unroll
        for (int i = 0; i < 8; ++i) {
          xv0[i] = *reinterpret_cast<const short8*>(xr0 + 32 * i);
          xv1[i] = *reinterpret_cast<const short8*>(xr1 + 32 * i);
        }
      } else {
        const float* xr0 = x + ((size_t)(n0 + arow)      * Tt + t) * Dd + kb + kg;
        const float* xr1 = x + ((size_t)(n0 + 16 + arow) * Tt + t) * Dd + kb + kg;
        #pragma unroll
        for (int i = 0; i < 8; ++i) {
          float4 a0 = *reinterpret_cast<const float4*>(xr0 + 32 * i);
          float4 a1 = *reinterpret_cast<const float4*>(xr0 + 32 * i + 4);
          float4 c0 = *reinterpret_cast<const float4*>(xr1 + 32 * i);
          float4 c1 = *reinterpret_cast<const float4*>(xr1 + 32 * i + 4);
          short8 v0, v1;
          v0[0]=(short)f2b(a0.x); v0[1]=(short)f2b(a0.y);
          v0[2]=(short)f2b(a0.z); v0[3]=(short)f2b(a0.w);
          v0[4]=(short)f2b(a1.x); v0[5]=(short)f2b(a1.y);
          v0[6]=(short)f2b(a1.z); v0[7]=(short)f2b(a1.w);
          v1[0]=(short)f2b(c0.x); v1[1]=(short)f2b(c0.y);
          v1[2]=(short)f2b(c0.z); v1[3]=(short)f2b(c0.w);
          v1[4]=(short)f2b(c1.x); v1[5]=(short)f2b(c1.y);
          v1[6]=(short)f2b(c1.z); v1[7]=(short)f2b(c1.w);
          xv0[i] = v0; xv1[i] = v1;
        }
      }
      #pragma unroll
      for (int i = 0; i < 8; ++i) {
        a00 = __builtin_amdgcn_mfma_f32_16x16x32_bf16(xv0[i], bx0[i], a00, 0, 0, 0);
        a01 = __builtin_amdgcn_mfma_f32_16x16x32_bf16(xv0[i], bx1[i], a01, 0, 0, 0);
        a10 = __builtin_amdgcn_mfma_f32_16x16x32_bf16(xv1[i], bx0[i], a10, 0, 0, 0);
        a11 = __builtin_amdgcn_mfma_f32_16x16x32_bf16(xv1[i], bx1[i], a11, 0, 0, 0);
      }
    } else if constexpr (MODE == 1) {
      const float* p = (const float*)xw + ((size_t)(n0 + nE) * Tt + t) * 4096 + jc0 + jj;
      xwv0 = p[0]; xwv1 = p[1024]; xwv2 = p[2048]; xwv3 = p[3072];
    } else {
      const u16* p = (const u16*)xw + ((size_t)(n0 + nE) * Tt + t) * 4096 + jc0 + jj;
      xwv0 = b2f(p[0]); xwv1 = b2f(p[1024]); xwv2 = b2f(p[2048]); xwv3 = b2f(p[3072]);
    }

    // ---- Gate A: per-wave poll of its 32 producers ----
    {
      const unsigned ep = (unsigned)(t + 1);
      bool rdy;
      do {
        unsigned f = 0xFFFFFFFFu;
        if (l < 32)
          f = __hip_atomic_load(&tFlg[32 * w + l], __ATOMIC_RELAXED,
                                __HIP_MEMORY_SCOPE_AGENT);
        rdy = (bool)__all(f >= ep);
        if (!rdy) __builtin_amdgcn_s_sleep(1);
      } while (!rdy);
    }
    // ---- Gate B: own-wg waves finished prior iteration (ex WAR safety) ----
    while (__hip_atomic_load(&pubcnt, __ATOMIC_RELAXED,
                             __HIP_MEMORY_SCOPE_WORKGROUP) < (unsigned)(4 * t))
      __builtin_amdgcn_s_sleep(1);
    asm volatile("" ::: "memory");

    // ---- h loads ----
    short8 hv0[8], hv1[8];
    {
      const u16* hr = hb + (size_t)arow * Hh + kb + kg;
      #pragma unroll
      for (int i = 0; i < 8; ++i) {
        if constexpr (HIST) {
          hv0[i] = *reinterpret_cast<const short8*>(hr + 32 * i);
          hv1[i] = *reinterpret_cast<const short8*>(hr + 16 * Hh + 32 * i);
        } else {
          hv0[i] = ldh16(hr + 32 * i);
          hv1[i] = ldh16(hr + 16 * Hh + 32 * i);
        }
      }
    }

    // ---- h MFMAs ----
    #pragma unroll
    for (int i = 0; i < 8; ++i) {
      a00 = __builtin_amdgcn_mfma_f32_16x16x32_bf16(hv0[i], bh0[i], a00, 0, 0, 0);
      a01 = __builtin_amdgcn_mfma_f32_16x16x32_bf16(hv0[i], bh1[i], a01, 0, 0, 0);
      a10 = __builtin_amdgcn_mfma_f32_16x16x32_bf16(hv1[i], bh0[i], a10, 0, 0, 0);
      a11 = __builtin_amdgcn_mfma_f32_16x16x32_bf16(hv1[i], bh1[i], a11, 0, 0, 0);
    }

    // ---- partial sums -> LDS ----
    #pragma unroll
    for (int q = 0; q < 4; ++q) {
      ex[w][ 0 + (l >> 4) * 4 + q][ 0 + (l & 15)] = a00[q];
      ex[w][ 0 + (l >> 4) * 4 + q][16 + (l & 15)] = a01[q];
      ex[w][16 + (l >> 4) * 4 + q][ 0 + (l & 15)] = a10[q];
      ex[w][16 + (l >> 4) * 4 + q][16 + (l & 15)] = a11[q];
    }
    bar_w();  // the ONLY per-step barrier

    // ---- gates, state update ----
    float pI = bI + xwv0, pF = bF + xwv1, pO = bO + xwv2, pG = bG + xwv3;
    #pragma unroll
    for (int wv = 0; wv < 4; ++wv) {
      pI += ex[wv][nE][ 0 + jj];
      pF += ex[wv][nE][ 8 + jj];
      pO += ex[wv][nE][16 + jj];
      pG += ex[wv][nE][24 + jj];
    }
    const float ig = sigm(pI), fg = sigm(pF), og = sigm(pO);
    const float gg = tanhfast(pG);
    c_reg = fg * c_reg + ig * gg;
    const float hv = og * tanhfast(c_reg);

    // ---- symmetric publish ----
    {
      int hb16 = (int)f2b(hv);
      int pb   = __shfl_xor(hb16, 1, 64);
      if ((tid & 1) == 0) {
        unsigned pk = (unsigned)(hb16 & 0xFFFF) | ((unsigned)(pb & 0xFFFF) << 16);
        __hip_atomic_store((unsigned*)(hbn + nE * Hh + jc0 + jj), pk,
                           __ATOMIC_RELAXED, __HIP_MEMORY_SCOPE_AGENT);
      }
      asm volatile("s_waitcnt vmcnt(0)" ::: "memory");
      if (l == 0) {
        unsigned old = __hip_atomic_fetch_add(&pubcnt, 1u, __ATOMIC_RELAXED,
                                              __HIP_MEMORY_SCOPE_WORKGROUP);
        if (old == (unsigned)(4 * t + 3) && t + 1 < Tt)
          __hip_atomic_store(&tFlg[r], (unsigned)(t + 2),
                             __ATOMIC_RELAXED, __HIP_MEMORY_SCOPE_AGENT);
      }
    }

    out[((size_t)(n0 + nE) * Tt + t) * Hh + jc0 + jj] = hv;
  }
}

extern "C" void kernel_launch(void* const* d_in, const int* in_sizes, int n_in,
                              void* d_out, int out_size, void* d_ws, size_t ws_size,
                              hipStream_t stream) {
  const float* x    = (const float*)d_in[0];
  const float* h0   = (const float*)d_in[1];
  const float* Wx   = (const float*)d_in[2];
  const float* Wh   = (const float*)d_in[3];
  const float* bias = (const float*)d_in[4];
  float* out = (float*)d_out;

  char* wsb = (char*)d_ws;
  unsigned* flg = (unsigned*)wsb;

  const size_t off_hist = (size_t)1 << 20;
  const size_t sz_hist  = (size_t)2 * Tt * MS * Hh * 2;     // 128 MiB
  const size_t off_xb   = off_hist + sz_hist;
  const size_t sz_xb    = (size_t)Nb * Tt * Dd * 2;         // 128 MiB
  const size_t off_wt   = off_xb + sz_xb;
  const size_t sz_wt    = (size_t)4096 * 1024 * 2;          // 8 MiB
  const size_t off_xw   = off_wt + sz_wt;
  const size_t sz_xw32  = (size_t)Nb * Tt * 4096 * 4;       // 1 GiB
  const size_t sz_xw16  = sz_xw32 / 2;

  int mode;
  if      (ws_size >= off_xw + sz_xw32) mode = 1;
  else if (ws_size >= off_xw + sz_xw16) mode = 2;
  else                                  mode = 0;

  u16* hmem;
  u16* xb  = (u16*)(wsb + off_xb);
  u16* wxt = (u16*)(wsb + off_wt);
  void* xw = (void*)(wsb + off_xw);

  hipMemsetAsync(wsb, 0, 40960, stream);

  if (mode >= 1) {
    hmem = (u16*)(wsb + off_hist);
    cvt_x_kernel<<<dim3((Nb * Tt * Dd) / (8 * TPB)), dim3(TPB), 0, stream>>>(x, xb);
    cvt_wt_kernel<<<dim3(2048), dim3(TPB), 0, stream>>>(Wx, wxt);
    if (mode == 1)
      gemm_xw<true><<<dim3(16384), dim3(TPB), 0, stream>>>(xb, wxt, xw);
    else
      gemm_xw<false><<<dim3(16384), dim3(TPB), 0, stream>>>(xb, wxt, xw);

    void* args[] = {(void*)&x, (void*)&xb, (void*)&h0, (void*)&Wx, (void*)&Wh,
                    (void*)&bias, (void*)&out, (void*)&hmem, (void*)&flg, (void*)&xw};
    const void* kfn = (mode == 1) ? (const void*)lstm_team<1, false, true>
                                  : (const void*)lstm_team<2, false, true>;
    hipLaunchCooperativeKernel(kfn, dim3(NWG), dim3(TPB), args, 0, stream);
    return;
  }

  // ---- mode 0: r10 fallback ----
  const bool use_hist = ws_size >= off_hist + sz_hist;
  const size_t xb0_off = use_hist ? off_xb : off_hist;
  const bool use_xb   = ws_size >= xb0_off + sz_xb;
  hmem = use_hist ? (u16*)(wsb + off_hist) : (u16*)(wsb + 65536);
  u16* xb0 = (u16*)(wsb + xb0_off);

  void* args[] = {(void*)&x, (void*)&xb0, (void*)&h0, (void*)&Wx, (void*)&Wh,
                  (void*)&bias, (void*)&out, (void*)&hmem, (void*)&flg, (void*)&xw};
  if (use_xb)
    cvt_x_kernel<<<dim3((Nb * Tt * Dd) / (8 * TPB)), dim3(TPB), 0, stream>>>(x, xb0);

  const void* kfn =
      use_hist ? (use_xb ? (const void*)lstm_team<0, true,  true>
                         : (const void*)lstm_team<0, false, true>)
               : (use_xb ? (const void*)lstm_team<0, true,  false>
                         : (const void*)lstm_team<0, false, false>);
  hipLaunchCooperativeKernel(kfn, dim3(NWG), dim3(TPB), args, 0, stream);
}